// Round 7
// baseline (233.767 us; speedup 1.0000x reference)
//
#include <hip/hip_runtime.h>
#include <stdint.h>

#define B_ 4
#define T_ 2048
#define C_ 1024
#define H_ 128
#define NEG_BIG -3.0e38f

typedef __attribute__((ext_vector_type(8))) short short8;
typedef __attribute__((ext_vector_type(4))) float f32x4;
typedef __attribute__((ext_vector_type(4))) unsigned short ushort4v;
typedef __attribute__((ext_vector_type(8))) unsigned short ushort8v;

// cheap bf16 cast: round-half-up, <=0.5 ULP (validated R6: absmax unchanged)
__device__ __forceinline__ unsigned short f2bf(float f) {
  union { float f; unsigned u; } cv; cv.f = f;
  return (unsigned short)((cv.u + 0x8000u) >> 16);
}

__device__ __forceinline__ float bf2f(unsigned short s) {
  union { unsigned u; float f; } cv; cv.u = ((unsigned)s) << 16;
  return cv.f;
}

// async global->LDS, 16 bytes per lane. LDS dest = wave-uniform base + lane*16.
__device__ __forceinline__ void gld16(const void* g, void* l) {
  __builtin_amdgcn_global_load_lds(
      (const __attribute__((address_space(1))) unsigned int*)g,
      (__attribute__((address_space(3))) unsigned int*)l, 16, 0, 0);
}

// scale = C^-0.5 = 1/32; folded with log2(e) for exp2-domain softmax
#define CSCALE 0.045084220027780106f

// ---------------------------------------------------------------------------
// Kernel 1: prep — cast x (fp32 [8192][1024]) to xb bf16, Wq|Wk|Wv
// (fp32 [1024][128]) to WbT bf16 [384][1024] (transposed), and zero the
// split-KV combine counters (block 8576). Memory-bound.
// ---------------------------------------------------------------------------
__global__ __launch_bounds__(256) void prep(const float* __restrict__ x,
                                            const float* __restrict__ Wq,
                                            const float* __restrict__ Wk,
                                            const float* __restrict__ Wv,
                                            unsigned short* __restrict__ xb,
                                            unsigned short* __restrict__ WbT,
                                            int* __restrict__ counters) {
  if (blockIdx.x < 8192) {
    const int base = (blockIdx.x * 256 + threadIdx.x) * 4;
    f32x4 v = *(const f32x4*)(x + base);
    ushort4v p;
    p[0] = f2bf(v[0]); p[1] = f2bf(v[1]); p[2] = f2bf(v[2]); p[3] = f2bf(v[3]);
    *(ushort4v*)(xb + base) = p;
  } else if (blockIdx.x < 8576) {
    const int i = (blockIdx.x - 8192) * 256 + threadIdx.x;  // 0..98303
    const int linear = i * 4;
    const int j = linear >> 10;
    const int k0 = linear & 1023;
    const float* W = (j < 128) ? Wq : (j < 256) ? Wk : Wv;
    const int h = j & 127;
    ushort4v p;
    p[0] = f2bf(W[(k0 + 0) * 128 + h]);
    p[1] = f2bf(W[(k0 + 1) * 128 + h]);
    p[2] = f2bf(W[(k0 + 2) * 128 + h]);
    p[3] = f2bf(W[(k0 + 3) * 128 + h]);
    *(ushort4v*)(WbT + linear) = p;
  } else {
    if (threadIdx.x < 128) counters[threadIdx.x] = 0;
  }
}

// ---------------------------------------------------------------------------
// Kernel 2: QKV projection — double-buffered LDS GEMM, BK=64, 1 barrier/iter.
// Tile 64M x 96N x 64K; grid = 128 rb x 4 cb = 512 blocks; 40 KB LDS.
// Rows stored as 8 chunks of 16B with swizzle slot = (chunk ^ row) & 7.
// Q written pre-scaled by CSCALE. V written transposed (VT[b][h][t]).
// (R5 structure — best measured.)
// ---------------------------------------------------------------------------
__global__ __launch_bounds__(256) void qkv_proj(const unsigned short* __restrict__ xb,
                                                const unsigned short* __restrict__ WbT,
                                                unsigned short* __restrict__ Qb,
                                                unsigned short* __restrict__ Kb,
                                                unsigned short* __restrict__ VT) {
  __shared__ unsigned short As[2][64 * 64];   // 8 KB each
  __shared__ unsigned short Bs[2][96 * 64];   // 12 KB each

  const int tid  = threadIdx.x;
  const int wave = tid >> 6, lane = tid & 63;
  const int quad = lane >> 4, l15 = lane & 15;
  const int rb = blockIdx.x >> 2, cb = blockIdx.x & 3;
  const int gm0 = rb * 64, gn0 = cb * 96;
  const int wm = wave >> 1, wn = wave & 1;

  const int srow = lane >> 3, sslot = lane & 7;

  int aoff[2][2], boff[3][2];
#pragma unroll
  for (int mt = 0; mt < 2; ++mt) {
    const int r = wm * 32 + mt * 16 + l15;
#pragma unroll
    for (int ks = 0; ks < 2; ++ks)
      aoff[mt][ks] = r * 64 + (((ks * 4 + quad) ^ r) & 7) * 8;
  }
#pragma unroll
  for (int nt = 0; nt < 3; ++nt) {
    const int r = wn * 48 + nt * 16 + l15;
#pragma unroll
    for (int ks = 0; ks < 2; ++ks)
      boff[nt][ks] = r * 64 + (((ks * 4 + quad) ^ r) & 7) * 8;
  }

  f32x4 acc[2][3];
  const f32x4 zero4 = {0.f, 0.f, 0.f, 0.f};
#pragma unroll
  for (int mt = 0; mt < 2; ++mt)
#pragma unroll
    for (int nt = 0; nt < 3; ++nt) acc[mt][nt] = zero4;

#define STAGE_QKV(buf, kb_)                                                        \
  {                                                                                \
    const int ko = (kb_) * 64;                                                     \
    _Pragma("unroll")                                                              \
    for (int q = 0; q < 2; ++q) {                                                  \
      const int row = wave * 16 + q * 8 + srow;                                    \
      gld16(xb + (size_t)(gm0 + row) * C_ + ko + ((sslot ^ row) & 7) * 8,          \
            &As[buf][(wave * 16 + q * 8) * 64]);                                   \
    }                                                                              \
    _Pragma("unroll")                                                              \
    for (int q = 0; q < 3; ++q) {                                                  \
      const int row = wave * 24 + q * 8 + srow;                                    \
      gld16(WbT + (size_t)(gn0 + row) * C_ + ko + ((sslot ^ row) & 7) * 8,         \
            &Bs[buf][(wave * 24 + q * 8) * 64]);                                   \
    }                                                                              \
  }

  STAGE_QKV(0, 0);

  for (int kb = 0; kb < 16; ++kb) {
    __syncthreads();
    if (kb + 1 < 16) STAGE_QKV((kb + 1) & 1, kb + 1);
    const unsigned short* Ac = As[kb & 1];
    const unsigned short* Bc = Bs[kb & 1];
#pragma unroll
    for (int ks = 0; ks < 2; ++ks) {
      short8 a0 = *(const short8*)(Ac + aoff[0][ks]);
      short8 a1 = *(const short8*)(Ac + aoff[1][ks]);
      short8 b0 = *(const short8*)(Bc + boff[0][ks]);
      short8 b1 = *(const short8*)(Bc + boff[1][ks]);
      short8 b2 = *(const short8*)(Bc + boff[2][ks]);
      acc[0][0] = __builtin_amdgcn_mfma_f32_16x16x32_bf16(a0, b0, acc[0][0], 0, 0, 0);
      acc[0][1] = __builtin_amdgcn_mfma_f32_16x16x32_bf16(a0, b1, acc[0][1], 0, 0, 0);
      acc[0][2] = __builtin_amdgcn_mfma_f32_16x16x32_bf16(a0, b2, acc[0][2], 0, 0, 0);
      acc[1][0] = __builtin_amdgcn_mfma_f32_16x16x32_bf16(a1, b0, acc[1][0], 0, 0, 0);
      acc[1][1] = __builtin_amdgcn_mfma_f32_16x16x32_bf16(a1, b1, acc[1][1], 0, 0, 0);
      acc[1][2] = __builtin_amdgcn_mfma_f32_16x16x32_bf16(a1, b2, acc[1][2], 0, 0, 0);
    }
  }
#undef STAGE_QKV

  // epilogue: D[row=quad*4+r][col=l15] per 16x16 tile
#pragma unroll
  for (int mt = 0; mt < 2; ++mt) {
    const int row0 = gm0 + wm * 32 + mt * 16 + quad * 4;
#pragma unroll
    for (int nt = 0; nt < 3; ++nt) {
      const int colbase = gn0 + wn * 48 + nt * 16;
      const int col = colbase + l15;
      if (colbase < 128) {          // Q (pre-scaled)
#pragma unroll
        for (int r = 0; r < 4; ++r)
          Qb[(size_t)(row0 + r) * H_ + col] = f2bf(acc[mt][nt][r] * CSCALE);
      } else if (colbase < 256) {   // K
#pragma unroll
        for (int r = 0; r < 4; ++r)
          Kb[(size_t)(row0 + r) * H_ + (col - 128)] = f2bf(acc[mt][nt][r]);
      } else {                      // V, transposed
        const int h = col - 256;
        const int bidx = row0 >> 11;
        const int t0 = row0 & 2047;
        ushort4v pk;
        pk[0] = f2bf(acc[mt][nt][0]); pk[1] = f2bf(acc[mt][nt][1]);
        pk[2] = f2bf(acc[mt][nt][2]); pk[3] = f2bf(acc[mt][nt][3]);
        *(ushort4v*)(VT + (size_t)(bidx * H_ + h) * T_ + t0) = pk;
      }
    }
  }
}

// ---------------------------------------------------------------------------
// Kernel 3: flash attention, S^T formulation, K AND V double-buffered in LDS
// via swizzled gld16; one barrier per KV tile of 64.  Split-KV combine is
// FUSED: last chunk-block per (b,j) (device-scope atomic counter) merges all
// partials and writes the final output — no separate attn2 dispatch.
// Grid 1024: b=bid&3, j=(bid>>2)&31, ch=bid>>7; valid iff ch*4<=j.
// ---------------------------------------------------------------------------
__global__ __launch_bounds__(256, 2) void attn1(const unsigned short* __restrict__ Qb,
                                                const unsigned short* __restrict__ Kb,
                                                const unsigned short* __restrict__ VT,
                                                unsigned short* __restrict__ Opart,
                                                float* __restrict__ mpart,
                                                float* __restrict__ lpart,
                                                int* __restrict__ counters,
                                                float* __restrict__ out) {
  __shared__ unsigned short Ks[2][64 * 128];   // 16 KB each; 16-slot rows
  __shared__ unsigned short Vs[2][128 * 64];   // 16 KB each; 8-slot rows
  __shared__ unsigned short Pls[4][16 * 72];   // 9 KB, per-wave P, pad 72
  __shared__ float Als[4][16];
  __shared__ int lastf;

  const int bid = blockIdx.x;
  const int b  = bid & 3;
  const int j  = (bid >> 2) & 31;
  const int ch = bid >> 7;
  if (ch * 4 > j) return;
  const int ntiles = min(4, j + 1 - ch * 4);

  const int tid  = threadIdx.x;
  const int wave = tid >> 6, lane = tid & 63;
  const int quad = lane >> 4, l15 = lane & 15;

  const unsigned short* qrow = Qb + (size_t)(b * T_ + j * 64 + wave * 16 + l15) * H_;
  short8 aq[4];
#pragma unroll
  for (int ks = 0; ks < 4; ++ks)
    aq[ks] = *(const short8*)(qrow + ks * 32 + quad * 8);

  const unsigned short* Kb_b = Kb + (size_t)(b * T_) * H_;
  const unsigned short* VT_b = VT + (size_t)(b * H_) * T_;

  const int k_row4 = lane >> 4, k_slot = lane & 15;
  const int v_row8 = lane >> 3, v_slot = lane & 7;

#define STAGE_KV(buf, kv0_)                                                        \
  {                                                                                \
    _Pragma("unroll")                                                              \
    for (int i = 0; i < 4; ++i) {                                                  \
      const int r = wave * 16 + i * 4 + k_row4;                                    \
      const int c2 = (k_slot & 8) | ((k_slot ^ r) & 7);                            \
      gld16(Kb_b + (size_t)((kv0_) + r) * H_ + c2 * 8,                             \
            &Ks[buf][(wave * 16 + i * 4) * 128]);                                  \
    }                                                                              \
    _Pragma("unroll")                                                              \
    for (int i = 0; i < 4; ++i) {                                                  \
      const int h = wave * 32 + i * 8 + v_row8;                                    \
      gld16(VT_b + (size_t)h * T_ + (kv0_) + ((v_slot ^ h) & 7) * 8,               \
            &Vs[buf][(wave * 32 + i * 8) * 64]);                                   \
    }                                                                              \
  }

  STAGE_KV(0, ch * 256);

  const f32x4 zero4 = {0.f, 0.f, 0.f, 0.f};
  f32x4 O[8];
#pragma unroll
  for (int nth = 0; nth < 8; ++nth) O[nth] = zero4;
  float m_ = NEG_BIG, l_ = 0.f;

  for (int t = 0; t < ntiles; ++t) {
    __syncthreads();
    const int kv0 = ch * 256 + t * 64;
    if (t + 1 < ntiles) STAGE_KV((t + 1) & 1, kv0 + 64);

    // ---- S^T = K . Q^T
    const unsigned short* kb = Ks[t & 1];
    f32x4 ST[4];
    ST[0] = zero4; ST[1] = zero4; ST[2] = zero4; ST[3] = zero4;
#pragma unroll
    for (int ntl = 0; ntl < 4; ++ntl) {
      const int kvr = ntl * 16 + l15;
#pragma unroll
      for (int ks = 0; ks < 4; ++ks) {
        const int c = ks * 4 + quad;
        const int slot = (c & 8) | ((c ^ kvr) & 7);
        short8 kf = *(const short8*)(kb + kvr * 128 + slot * 8);
        ST[ntl] = __builtin_amdgcn_mfma_f32_16x16x32_bf16(kf, aq[ks], ST[ntl], 0, 0, 0);
      }
    }

    // ---- causal mask (diagonal tile only)
    if (ch * 4 + t == j) {
      const int ql = j * 64 + wave * 16 + l15;
#pragma unroll
      for (int ntl = 0; ntl < 4; ++ntl)
#pragma unroll
        for (int r = 0; r < 4; ++r) {
          const int kl = kv0 + ntl * 16 + quad * 4 + r;
          if (kl > ql) ST[ntl][r] = NEG_BIG;
        }
    }

    // ---- softmax (per lane q=l15)
    float vmax = ST[0][0];
#pragma unroll
    for (int ntl = 0; ntl < 4; ++ntl)
#pragma unroll
      for (int r = 0; r < 4; ++r) vmax = fmaxf(vmax, ST[ntl][r]);
    vmax = fmaxf(vmax, __shfl_xor(vmax, 16));
    vmax = fmaxf(vmax, __shfl_xor(vmax, 32));
    const float mn = fmaxf(m_, vmax);
    const float alpha = __builtin_amdgcn_exp2f(m_ - mn);
    m_ = mn;
    float s = 0.f;
#pragma unroll
    for (int ntl = 0; ntl < 4; ++ntl)
#pragma unroll
      for (int r = 0; r < 4; ++r) {
        const float p = __builtin_amdgcn_exp2f(ST[ntl][r] - mn);
        ST[ntl][r] = p;
        s += p;
      }
    s += __shfl_xor(s, 16);
    s += __shfl_xor(s, 32);
    l_ = l_ * alpha + s;

    // ---- P -> LDS ([q][kv] layout)
#pragma unroll
    for (int ntl = 0; ntl < 4; ++ntl) {
      ushort4v pk;
      pk[0] = f2bf(ST[ntl][0]); pk[1] = f2bf(ST[ntl][1]);
      pk[2] = f2bf(ST[ntl][2]); pk[3] = f2bf(ST[ntl][3]);
      *(ushort4v*)(&Pls[wave][l15 * 72 + ntl * 16 + quad * 4]) = pk;
    }

    // ---- O rescale by alpha
    if (lane < 16) Als[wave][lane] = alpha;
    if (!__all(alpha == 1.f)) {
      f32x4 al4 = *(const f32x4*)&Als[wave][quad * 4];
#pragma unroll
      for (int nth = 0; nth < 8; ++nth)
#pragma unroll
        for (int r = 0; r < 4; ++r) O[nth][r] *= al4[r];
    }

    // ---- O += P . V
    const unsigned short* vb = Vs[t & 1];
    short8 ap0 = *(const short8*)(&Pls[wave][l15 * 72 + quad * 8]);
    short8 ap1 = *(const short8*)(&Pls[wave][l15 * 72 + 32 + quad * 8]);
#pragma unroll
    for (int nth = 0; nth < 8; ++nth) {
      const int h = nth * 16 + l15;
      short8 v0 = *(const short8*)(vb + h * 64 + ((quad ^ h) & 7) * 8);
      short8 v1 = *(const short8*)(vb + h * 64 + (((4 + quad) ^ h) & 7) * 8);
      O[nth] = __builtin_amdgcn_mfma_f32_16x16x32_bf16(ap0, v0, O[nth], 0, 0, 0);
      O[nth] = __builtin_amdgcn_mfma_f32_16x16x32_bf16(ap1, v1, O[nth], 0, 0, 0);
    }
  }
#undef STAGE_KV

  // ---- epilogue
  if ((j >> 2) == 0) {  // single chunk: final output directly
    if (lane < 16) Als[wave][lane] = 1.0f / l_;
    f32x4 li4 = *(const f32x4*)&Als[wave][quad * 4];
    float* op = out + (size_t)(b * T_ + j * 64 + wave * 16) * H_;
#pragma unroll
    for (int nth = 0; nth < 8; ++nth)
#pragma unroll
      for (int r = 0; r < 4; ++r)
        op[(quad * 4 + r) * H_ + nth * 16 + l15] = O[nth][r] * li4[r];
  } else {              // multi-chunk: write partial, last block combines
    const int pid = (b * 32 + j) * 8 + ch;
    unsigned short* po = Opart + (size_t)(pid * 64 + wave * 16) * H_;
#pragma unroll
    for (int nth = 0; nth < 8; ++nth)
#pragma unroll
      for (int r = 0; r < 4; ++r)
        po[(quad * 4 + r) * H_ + nth * 16 + l15] = f2bf(O[nth][r]);
    if (lane < 16) {
      mpart[pid * 64 + wave * 16 + lane] = m_;
      lpart[pid * 64 + wave * 16 + lane] = l_;
    }

    const int nch = (j >> 2) + 1;        // 2..8
    __threadfence();                     // release: partials visible device-wide
    if (tid == 0) {
      const int old = atomicAdd(&counters[b * 32 + j], 1);
      lastf = (old == nch - 1);
    }
    __syncthreads();
    if (lastf) {
      __threadfence();                   // acquire: see other blocks' partials
      const int pbase = (b * 32 + j) * 8;
      const int qh = tid >> 4;
      const int h0 = (tid & 15) * 8;
#pragma unroll
      for (int i = 0; i < 4; ++i) {
        const int q = qh + i * 16;       // 0..63
        float m_fin = NEG_BIG;
        for (int c2 = 0; c2 < nch; ++c2)
          m_fin = fmaxf(m_fin, mpart[(pbase + c2) * 64 + q]);
        float lf = 0.f;
        float o[8];
#pragma unroll
        for (int c = 0; c < 8; ++c) o[c] = 0.f;
        for (int c2 = 0; c2 < nch; ++c2) {
          const int pid2 = pbase + c2;
          const float sc = __builtin_amdgcn_exp2f(mpart[pid2 * 64 + q] - m_fin);
          lf += sc * lpart[pid2 * 64 + q];
          ushort8v pv = *(const ushort8v*)(Opart + (size_t)(pid2 * 64 + q) * H_ + h0);
#pragma unroll
          for (int c = 0; c < 8; ++c) o[c] += sc * bf2f(pv[c]);
        }
        const float inv = 1.0f / lf;
        float* op = out + (size_t)(b * T_ + j * 64 + q) * H_ + h0;
        f32x4 v0 = {o[0] * inv, o[1] * inv, o[2] * inv, o[3] * inv};
        f32x4 v1 = {o[4] * inv, o[5] * inv, o[6] * inv, o[7] * inv};
        *(f32x4*)(op) = v0;
        *(f32x4*)(op + 4) = v1;
      }
    }
  }
}

// ---------------------------------------------------------------------------
extern "C" void kernel_launch(void* const* d_in, const int* in_sizes, int n_in,
                              void* d_out, int out_size, void* d_ws, size_t ws_size,
                              hipStream_t stream) {
  const float* x  = (const float*)d_in[0];
  const float* Wq = (const float*)d_in[1];
  const float* Wk = (const float*)d_in[2];
  const float* Wv = (const float*)d_in[3];
  float* out = (float*)d_out;

  char* ws = (char*)d_ws;
  unsigned short* xb  = (unsigned short*)(ws);              // [0, 16 MB)
  unsigned short* WbT = (unsigned short*)(ws + 16777216);   // 768 KB
  unsigned short* Qb  = (unsigned short*)(ws + 17563648);   // 2 MB
  unsigned short* Kb  = (unsigned short*)(ws + 19660800);   // 2 MB
  unsigned short* VT  = (unsigned short*)(ws + 21757952);   // 2 MB -> end 23855104
  // attn partials OVERLAY xb/WbT (dead after qkv_proj; stream-ordered)
  unsigned short* Opart = (unsigned short*)(ws);            // 16 MB
  float* mpart = (float*)(ws + 16777216);                   // 256 KB
  float* lpart = (float*)(ws + 17039360);                   // 256 KB (< 17563648)
  int* counters = (int*)(ws + 25165824);                    // 512 B (past VT end)

  prep<<<dim3(8577), dim3(256), 0, stream>>>(x, Wq, Wk, Wv, xb, WbT, counters);
  qkv_proj<<<dim3(512), dim3(256), 0, stream>>>(xb, WbT, Qb, Kb, VT);
  attn1<<<dim3(1024), dim3(256), 0, stream>>>(Qb, Kb, VT, Opart, mpart, lpart,
                                              counters, out);
}

// Round 8
// 142.578 us; speedup vs baseline: 1.6396x; 1.6396x over previous
//
#include <hip/hip_runtime.h>
#include <stdint.h>

#define B_ 4
#define T_ 2048
#define C_ 1024
#define H_ 128
#define NEG_BIG -3.0e38f

typedef __attribute__((ext_vector_type(8))) short short8;
typedef __attribute__((ext_vector_type(4))) float f32x4;
typedef __attribute__((ext_vector_type(4))) unsigned short ushort4v;
typedef __attribute__((ext_vector_type(8))) unsigned short ushort8v;

// cheap bf16 cast: round-half-up, <=0.5 ULP (validated R6/R7: absmax unchanged)
__device__ __forceinline__ unsigned short f2bf(float f) {
  union { float f; unsigned u; } cv; cv.f = f;
  return (unsigned short)((cv.u + 0x8000u) >> 16);
}

__device__ __forceinline__ float bf2f(unsigned short s) {
  union { unsigned u; float f; } cv; cv.u = ((unsigned)s) << 16;
  return cv.f;
}

// async global->LDS, 16 bytes per lane. LDS dest = wave-uniform base + lane*16.
__device__ __forceinline__ void gld16(const void* g, void* l) {
  __builtin_amdgcn_global_load_lds(
      (const __attribute__((address_space(1))) unsigned int*)g,
      (__attribute__((address_space(3))) unsigned int*)l, 16, 0, 0);
}

// scale = C^-0.5 = 1/32; folded with log2(e) for exp2-domain softmax
#define CSCALE 0.045084220027780106f

// ---------------------------------------------------------------------------
// Kernel 1: prep_w — cast Wq|Wk|Wv (fp32 [1024][128]) to WbT bf16 [384][1024]
// (transposed so B-fragments are contiguous). Tiny.
// ---------------------------------------------------------------------------
__global__ __launch_bounds__(256) void prep_w(const float* __restrict__ Wq,
                                              const float* __restrict__ Wk,
                                              const float* __restrict__ Wv,
                                              unsigned short* __restrict__ WbT) {
  const int i = blockIdx.x * 256 + threadIdx.x;   // 0..98303
  const int linear = i * 4;
  const int j = linear >> 10;
  const int k0 = linear & 1023;
  const float* W = (j < 128) ? Wq : (j < 256) ? Wk : Wv;
  const int h = j & 127;
  ushort4v p;
  p[0] = f2bf(W[(k0 + 0) * 128 + h]);
  p[1] = f2bf(W[(k0 + 1) * 128 + h]);
  p[2] = f2bf(W[(k0 + 2) * 128 + h]);
  p[3] = f2bf(W[(k0 + 3) * 128 + h]);
  *(ushort4v*)(WbT + linear) = p;
}

// ---------------------------------------------------------------------------
// Kernel 2: fused x-cast + QKV projection. Grid 512 = 256 M-tiles(32) x 2
// N-halves(192).  A: x fp32 loaded per-block (rows exclusive to the M-tile),
// cast in-register ONCE, ds_write_b128 to bf16 LDS (swizzled slots).
// B: bf16 gld16 from WbT.  BK=64 double-buffered, 1 barrier/iter, 56 KB LDS.
// Wave owns 32M x 48N (2 mt x 3 nt accs).  Q pre-scaled by CSCALE; V stored
// transposed VT[b][h][t].
// ---------------------------------------------------------------------------
__global__ __launch_bounds__(256) void qkv_proj(const float* __restrict__ x,
                                                const unsigned short* __restrict__ WbT,
                                                unsigned short* __restrict__ Qb,
                                                unsigned short* __restrict__ Kb,
                                                unsigned short* __restrict__ VT) {
  __shared__ unsigned short As[2][32 * 64];    // 4 KB each
  __shared__ unsigned short Bs[2][192 * 64];   // 24 KB each

  const int tid  = threadIdx.x;
  const int wave = tid >> 6, lane = tid & 63;
  const int quad = lane >> 4, l15 = lane & 15;
  const int rb = blockIdx.x >> 1, cb = blockIdx.x & 1;
  const int gm0 = rb * 32, gn0 = cb * 192;

  // A staging: thread -> (row = tid>>3, chunk = tid&7)
  const int ar = tid >> 3, ac = tid & 7;
  const float* gA = x + (size_t)(gm0 + ar) * C_ + ac * 8;
  unsigned short* lA = (unsigned short*)&As[0][0] + ar * 64 + ((ac ^ ar) & 7) * 8;
  const int lAstride = 32 * 64;  // buffer stride in shorts

  // B staging: lane -> (srow = lane>>3, sslot = lane&7); wave covers 48 rows
  const int srow = lane >> 3, sslot = lane & 7;

  // fragment read offsets (shorts)
  int aoff[2][2], boff[3][2];
#pragma unroll
  for (int mt = 0; mt < 2; ++mt) {
    const int r = mt * 16 + l15;
#pragma unroll
    for (int ks = 0; ks < 2; ++ks)
      aoff[mt][ks] = r * 64 + (((ks * 4 + quad) ^ r) & 7) * 8;
  }
#pragma unroll
  for (int nt = 0; nt < 3; ++nt) {
    const int r = wave * 48 + nt * 16 + l15;
#pragma unroll
    for (int ks = 0; ks < 2; ++ks)
      boff[nt][ks] = r * 64 + (((ks * 4 + quad) ^ r) & 7) * 8;
  }

  f32x4 acc[2][3];
  const f32x4 zero4 = {0.f, 0.f, 0.f, 0.f};
#pragma unroll
  for (int mt = 0; mt < 2; ++mt)
#pragma unroll
    for (int nt = 0; nt < 3; ++nt) acc[mt][nt] = zero4;

#define STAGE_B(buf, kb_)                                                          \
  {                                                                                \
    const int ko = (kb_) * 64;                                                     \
    _Pragma("unroll")                                                              \
    for (int q = 0; q < 6; ++q) {                                                  \
      const int row = wave * 48 + q * 8 + srow;                                    \
      gld16(WbT + (size_t)(gn0 + row) * C_ + ko + ((sslot ^ row) & 7) * 8,         \
            &Bs[buf][(wave * 48 + q * 8) * 64]);                                   \
    }                                                                              \
  }

  // preload tile 0
  {
    f32x4 va = *(const f32x4*)(gA);
    f32x4 vb = *(const f32x4*)(gA + 4);
    STAGE_B(0, 0);
    short8 aw;
#pragma unroll
    for (int e = 0; e < 4; ++e) {
      aw[e]     = (short)f2bf(va[e]);
      aw[4 + e] = (short)f2bf(vb[e]);
    }
    *(short8*)lA = aw;
  }

  for (int kb = 0; kb < 16; ++kb) {
    __syncthreads();               // buf[kb&1] fully staged; other buf free
    const int cur = kb & 1, nxt = cur ^ 1;
    f32x4 va, vb;
    if (kb + 1 < 16) {             // issue next-tile loads early
      const int ko = (kb + 1) * 64;
      va = *(const f32x4*)(gA + ko);
      vb = *(const f32x4*)(gA + ko + 4);
      STAGE_B(nxt, kb + 1);
    }
    const unsigned short* Ac = As[cur];
    const unsigned short* Bc = Bs[cur];
#pragma unroll
    for (int ks = 0; ks < 2; ++ks) {
      short8 a0 = *(const short8*)(Ac + aoff[0][ks]);
      short8 a1 = *(const short8*)(Ac + aoff[1][ks]);
      short8 b0 = *(const short8*)(Bc + boff[0][ks]);
      short8 b1 = *(const short8*)(Bc + boff[1][ks]);
      short8 b2 = *(const short8*)(Bc + boff[2][ks]);
      acc[0][0] = __builtin_amdgcn_mfma_f32_16x16x32_bf16(a0, b0, acc[0][0], 0, 0, 0);
      acc[0][1] = __builtin_amdgcn_mfma_f32_16x16x32_bf16(a0, b1, acc[0][1], 0, 0, 0);
      acc[0][2] = __builtin_amdgcn_mfma_f32_16x16x32_bf16(a0, b2, acc[0][2], 0, 0, 0);
      acc[1][0] = __builtin_amdgcn_mfma_f32_16x16x32_bf16(a1, b0, acc[1][0], 0, 0, 0);
      acc[1][1] = __builtin_amdgcn_mfma_f32_16x16x32_bf16(a1, b1, acc[1][1], 0, 0, 0);
      acc[1][2] = __builtin_amdgcn_mfma_f32_16x16x32_bf16(a1, b2, acc[1][2], 0, 0, 0);
    }
    if (kb + 1 < 16) {             // convert + write next A tile (other buffer)
      short8 aw;
#pragma unroll
      for (int e = 0; e < 4; ++e) {
        aw[e]     = (short)f2bf(va[e]);
        aw[4 + e] = (short)f2bf(vb[e]);
      }
      *(short8*)(lA + nxt * lAstride) = aw;
    }
  }
#undef STAGE_B

  // epilogue: D[row=quad*4+r][col=l15] per 16x16 tile
#pragma unroll
  for (int mt = 0; mt < 2; ++mt) {
    const int row0 = gm0 + mt * 16 + quad * 4;
#pragma unroll
    for (int nt = 0; nt < 3; ++nt) {
      const int colbase = gn0 + wave * 48 + nt * 16;
      const int col = colbase + l15;
      if (colbase < 128) {          // Q (pre-scaled)
#pragma unroll
        for (int r = 0; r < 4; ++r)
          Qb[(size_t)(row0 + r) * H_ + col] = f2bf(acc[mt][nt][r] * CSCALE);
      } else if (colbase < 256) {   // K
#pragma unroll
        for (int r = 0; r < 4; ++r)
          Kb[(size_t)(row0 + r) * H_ + (col - 128)] = f2bf(acc[mt][nt][r]);
      } else {                      // V, transposed
        const int h = col - 256;
        const int bidx = row0 >> 11;
        const int t0 = row0 & 2047;
        ushort4v pk;
        pk[0] = f2bf(acc[mt][nt][0]); pk[1] = f2bf(acc[mt][nt][1]);
        pk[2] = f2bf(acc[mt][nt][2]); pk[3] = f2bf(acc[mt][nt][3]);
        *(ushort4v*)(VT + (size_t)(bidx * H_ + h) * T_ + t0) = pk;
      }
    }
  }
}

// ---------------------------------------------------------------------------
// Kernel 3: flash attention stage 1 (R5-exact, best measured). S^T form,
// K AND V double-buffered in LDS via swizzled gld16; one barrier per KV tile.
// Grid 1024: b=bid&3, j=(bid>>2)&31, ch=bid>>7; valid iff ch*4<=j.
// ---------------------------------------------------------------------------
__global__ __launch_bounds__(256, 2) void attn1(const unsigned short* __restrict__ Qb,
                                                const unsigned short* __restrict__ Kb,
                                                const unsigned short* __restrict__ VT,
                                                unsigned short* __restrict__ Opart,
                                                float* __restrict__ mpart,
                                                float* __restrict__ lpart,
                                                float* __restrict__ out) {
  __shared__ unsigned short Ks[2][64 * 128];   // 16 KB each; 16-slot rows
  __shared__ unsigned short Vs[2][128 * 64];   // 16 KB each; 8-slot rows
  __shared__ unsigned short Pls[4][16 * 72];   // 9 KB, per-wave P, pad 72
  __shared__ float Als[4][16];

  const int bid = blockIdx.x;
  const int b  = bid & 3;
  const int j  = (bid >> 2) & 31;
  const int ch = bid >> 7;
  if (ch * 4 > j) return;
  const int ntiles = min(4, j + 1 - ch * 4);

  const int tid  = threadIdx.x;
  const int wave = tid >> 6, lane = tid & 63;
  const int quad = lane >> 4, l15 = lane & 15;

  const unsigned short* qrow = Qb + (size_t)(b * T_ + j * 64 + wave * 16 + l15) * H_;
  short8 aq[4];
#pragma unroll
  for (int ks = 0; ks < 4; ++ks)
    aq[ks] = *(const short8*)(qrow + ks * 32 + quad * 8);

  const unsigned short* Kb_b = Kb + (size_t)(b * T_) * H_;
  const unsigned short* VT_b = VT + (size_t)(b * H_) * T_;

  const int k_row4 = lane >> 4, k_slot = lane & 15;
  const int v_row8 = lane >> 3, v_slot = lane & 7;

#define STAGE_KV(buf, kv0_)                                                        \
  {                                                                                \
    _Pragma("unroll")                                                              \
    for (int i = 0; i < 4; ++i) {                                                  \
      const int r = wave * 16 + i * 4 + k_row4;                                    \
      const int c2 = (k_slot & 8) | ((k_slot ^ r) & 7);                            \
      gld16(Kb_b + (size_t)((kv0_) + r) * H_ + c2 * 8,                             \
            &Ks[buf][(wave * 16 + i * 4) * 128]);                                  \
    }                                                                              \
    _Pragma("unroll")                                                              \
    for (int i = 0; i < 4; ++i) {                                                  \
      const int h = wave * 32 + i * 8 + v_row8;                                    \
      gld16(VT_b + (size_t)h * T_ + (kv0_) + ((v_slot ^ h) & 7) * 8,               \
            &Vs[buf][(wave * 32 + i * 8) * 64]);                                   \
    }                                                                              \
  }

  STAGE_KV(0, ch * 256);

  const f32x4 zero4 = {0.f, 0.f, 0.f, 0.f};
  f32x4 O[8];
#pragma unroll
  for (int nth = 0; nth < 8; ++nth) O[nth] = zero4;
  float m_ = NEG_BIG, l_ = 0.f;

  for (int t = 0; t < ntiles; ++t) {
    __syncthreads();
    const int kv0 = ch * 256 + t * 64;
    if (t + 1 < ntiles) STAGE_KV((t + 1) & 1, kv0 + 64);

    // ---- S^T = K . Q^T
    const unsigned short* kb = Ks[t & 1];
    f32x4 ST[4];
    ST[0] = zero4; ST[1] = zero4; ST[2] = zero4; ST[3] = zero4;
#pragma unroll
    for (int ntl = 0; ntl < 4; ++ntl) {
      const int kvr = ntl * 16 + l15;
#pragma unroll
      for (int ks = 0; ks < 4; ++ks) {
        const int c = ks * 4 + quad;
        const int slot = (c & 8) | ((c ^ kvr) & 7);
        short8 kf = *(const short8*)(kb + kvr * 128 + slot * 8);
        ST[ntl] = __builtin_amdgcn_mfma_f32_16x16x32_bf16(kf, aq[ks], ST[ntl], 0, 0, 0);
      }
    }

    // ---- causal mask (diagonal tile only)
    if (ch * 4 + t == j) {
      const int ql = j * 64 + wave * 16 + l15;
#pragma unroll
      for (int ntl = 0; ntl < 4; ++ntl)
#pragma unroll
        for (int r = 0; r < 4; ++r) {
          const int kl = kv0 + ntl * 16 + quad * 4 + r;
          if (kl > ql) ST[ntl][r] = NEG_BIG;
        }
    }

    // ---- softmax (per lane q=l15)
    float vmax = ST[0][0];
#pragma unroll
    for (int ntl = 0; ntl < 4; ++ntl)
#pragma unroll
      for (int r = 0; r < 4; ++r) vmax = fmaxf(vmax, ST[ntl][r]);
    vmax = fmaxf(vmax, __shfl_xor(vmax, 16));
    vmax = fmaxf(vmax, __shfl_xor(vmax, 32));
    const float mn = fmaxf(m_, vmax);
    const float alpha = __builtin_amdgcn_exp2f(m_ - mn);
    m_ = mn;
    float s = 0.f;
#pragma unroll
    for (int ntl = 0; ntl < 4; ++ntl)
#pragma unroll
      for (int r = 0; r < 4; ++r) {
        const float p = __builtin_amdgcn_exp2f(ST[ntl][r] - mn);
        ST[ntl][r] = p;
        s += p;
      }
    s += __shfl_xor(s, 16);
    s += __shfl_xor(s, 32);
    l_ = l_ * alpha + s;

    // ---- P -> LDS ([q][kv] layout)
#pragma unroll
    for (int ntl = 0; ntl < 4; ++ntl) {
      ushort4v pk;
      pk[0] = f2bf(ST[ntl][0]); pk[1] = f2bf(ST[ntl][1]);
      pk[2] = f2bf(ST[ntl][2]); pk[3] = f2bf(ST[ntl][3]);
      *(ushort4v*)(&Pls[wave][l15 * 72 + ntl * 16 + quad * 4]) = pk;
    }

    // ---- O rescale by alpha
    if (lane < 16) Als[wave][lane] = alpha;
    if (!__all(alpha == 1.f)) {
      f32x4 al4 = *(const f32x4*)&Als[wave][quad * 4];
#pragma unroll
      for (int nth = 0; nth < 8; ++nth)
#pragma unroll
        for (int r = 0; r < 4; ++r) O[nth][r] *= al4[r];
    }

    // ---- O += P . V
    const unsigned short* vb = Vs[t & 1];
    short8 ap0 = *(const short8*)(&Pls[wave][l15 * 72 + quad * 8]);
    short8 ap1 = *(const short8*)(&Pls[wave][l15 * 72 + 32 + quad * 8]);
#pragma unroll
    for (int nth = 0; nth < 8; ++nth) {
      const int h = nth * 16 + l15;
      short8 v0 = *(const short8*)(vb + h * 64 + ((quad ^ h) & 7) * 8);
      short8 v1 = *(const short8*)(vb + h * 64 + (((4 + quad) ^ h) & 7) * 8);
      O[nth] = __builtin_amdgcn_mfma_f32_16x16x32_bf16(ap0, v0, O[nth], 0, 0, 0);
      O[nth] = __builtin_amdgcn_mfma_f32_16x16x32_bf16(ap1, v1, O[nth], 0, 0, 0);
    }
  }
#undef STAGE_KV

  // ---- epilogue
  if ((j >> 2) == 0) {
    if (lane < 16) Als[wave][lane] = 1.0f / l_;
    f32x4 li4 = *(const f32x4*)&Als[wave][quad * 4];
    float* op = out + (size_t)(b * T_ + j * 64 + wave * 16) * H_;
#pragma unroll
    for (int nth = 0; nth < 8; ++nth)
#pragma unroll
      for (int r = 0; r < 4; ++r)
        op[(quad * 4 + r) * H_ + nth * 16 + l15] = O[nth][r] * li4[r];
  } else {
    const int pid = (b * 32 + j) * 8 + ch;
    unsigned short* po = Opart + (size_t)(pid * 64 + wave * 16) * H_;
#pragma unroll
    for (int nth = 0; nth < 8; ++nth)
#pragma unroll
      for (int r = 0; r < 4; ++r)
        po[(quad * 4 + r) * H_ + nth * 16 + l15] = f2bf(O[nth][r]);
    if (lane < 16) {
      mpart[pid * 64 + wave * 16 + lane] = m_;
      lpart[pid * 64 + wave * 16 + lane] = l_;
    }
  }
}

// ---------------------------------------------------------------------------
// Kernel 4: stage-2 combine for j >= 4. Grid = 4 b x 28 j = 112 blocks.
// ---------------------------------------------------------------------------
__global__ __launch_bounds__(256) void attn2(const unsigned short* __restrict__ Opart,
                                             const float* __restrict__ mpart,
                                             const float* __restrict__ lpart,
                                             float* __restrict__ out) {
  const int b = blockIdx.x & 3;
  const int j = 4 + (blockIdx.x >> 2);
  const int nch = (j >> 2) + 1;       // 2..8
  const int tid = threadIdx.x;
  const int qh = tid >> 4;            // 0..15
  const int h0 = (tid & 15) * 8;
  const int pbase = (b * 32 + j) * 8;

#pragma unroll
  for (int i = 0; i < 4; ++i) {
    const int q = qh + i * 16;        // 0..63
    float m_fin = NEG_BIG;
    for (int ch = 0; ch < nch; ++ch)
      m_fin = fmaxf(m_fin, mpart[(pbase + ch) * 64 + q]);
    float lf = 0.f;
    float o[8];
#pragma unroll
    for (int c = 0; c < 8; ++c) o[c] = 0.f;
    for (int ch = 0; ch < nch; ++ch) {
      const int pid = pbase + ch;
      const float sc = __builtin_amdgcn_exp2f(mpart[pid * 64 + q] - m_fin);
      lf += sc * lpart[pid * 64 + q];
      ushort8v pv = *(const ushort8v*)(Opart + (size_t)(pid * 64 + q) * H_ + h0);
#pragma unroll
      for (int c = 0; c < 8; ++c) o[c] += sc * bf2f(pv[c]);
    }
    const float inv = 1.0f / lf;
    float* op = out + (size_t)(b * T_ + j * 64 + q) * H_ + h0;
    f32x4 v0 = {o[0] * inv, o[1] * inv, o[2] * inv, o[3] * inv};
    f32x4 v1 = {o[4] * inv, o[5] * inv, o[6] * inv, o[7] * inv};
    *(f32x4*)(op) = v0;
    *(f32x4*)(op + 4) = v1;
  }
}

// ---------------------------------------------------------------------------
extern "C" void kernel_launch(void* const* d_in, const int* in_sizes, int n_in,
                              void* d_out, int out_size, void* d_ws, size_t ws_size,
                              hipStream_t stream) {
  const float* x  = (const float*)d_in[0];
  const float* Wq = (const float*)d_in[1];
  const float* Wk = (const float*)d_in[2];
  const float* Wv = (const float*)d_in[3];
  float* out = (float*)d_out;

  char* ws = (char*)d_ws;
  unsigned short* Opart = (unsigned short*)(ws);            // [0, 16 MB)
  float* mpart = (float*)(ws + 16777216);                   // 256 KB
  float* lpart = (float*)(ws + 17039360);                   // 256 KB
  unsigned short* WbT = (unsigned short*)(ws + 17563648);   // 768 KB
  unsigned short* Qb  = (unsigned short*)(ws + 18350080);   // 2 MB
  unsigned short* Kb  = (unsigned short*)(ws + 20447232);   // 2 MB
  unsigned short* VT  = (unsigned short*)(ws + 22544384);   // 2 MB -> end 24641536

  prep_w<<<dim3(384), dim3(256), 0, stream>>>(Wq, Wk, Wv, WbT);
  qkv_proj<<<dim3(512), dim3(256), 0, stream>>>(x, WbT, Qb, Kb, VT);
  attn1<<<dim3(1024), dim3(256), 0, stream>>>(Qb, Kb, VT, Opart, mpart, lpart, out);
  attn2<<<dim3(112), dim3(256), 0, stream>>>(Opart, mpart, lpart, out);
}

// Round 9
// 137.192 us; speedup vs baseline: 1.7039x; 1.0393x over previous
//
#include <hip/hip_runtime.h>
#include <stdint.h>

#define B_ 4
#define T_ 2048
#define C_ 1024
#define H_ 128
#define NEG_BIG -3.0e38f

typedef __attribute__((ext_vector_type(8))) short short8;
typedef __attribute__((ext_vector_type(4))) float f32x4;
typedef __attribute__((ext_vector_type(4))) unsigned short ushort4v;
typedef __attribute__((ext_vector_type(8))) unsigned short ushort8v;

// cheap bf16 cast: round-half-up, <=0.5 ULP (validated R6-R8: absmax unchanged)
__device__ __forceinline__ unsigned short f2bf(float f) {
  union { float f; unsigned u; } cv; cv.f = f;
  return (unsigned short)((cv.u + 0x8000u) >> 16);
}

__device__ __forceinline__ float bf2f(unsigned short s) {
  union { unsigned u; float f; } cv; cv.u = ((unsigned)s) << 16;
  return cv.f;
}

// async global->LDS, 16 bytes per lane. LDS dest = wave-uniform base + lane*16.
__device__ __forceinline__ void gld16(const void* g, void* l) {
  __builtin_amdgcn_global_load_lds(
      (const __attribute__((address_space(1))) unsigned int*)g,
      (__attribute__((address_space(3))) unsigned int*)l, 16, 0, 0);
}

// scale = C^-0.5 = 1/32; folded with log2(e) for exp2-domain softmax
#define CSCALE 0.045084220027780106f

// ---------------------------------------------------------------------------
// Kernel 1: prep — cast x (fp32 [8192][1024]) to xb bf16, and Wq|Wk|Wv
// (fp32 [1024][128]) to WbT bf16 [384][1024] (transposed). Memory-bound.
// (R5-proven version.)
// ---------------------------------------------------------------------------
__global__ __launch_bounds__(256) void prep(const float* __restrict__ x,
                                            const float* __restrict__ Wq,
                                            const float* __restrict__ Wk,
                                            const float* __restrict__ Wv,
                                            unsigned short* __restrict__ xb,
                                            unsigned short* __restrict__ WbT) {
  if (blockIdx.x < 8192) {
    const int base = (blockIdx.x * 256 + threadIdx.x) * 4;
    f32x4 v = *(const f32x4*)(x + base);
    ushort4v p;
    p[0] = f2bf(v[0]); p[1] = f2bf(v[1]); p[2] = f2bf(v[2]); p[3] = f2bf(v[3]);
    *(ushort4v*)(xb + base) = p;
  } else {
    const int i = (blockIdx.x - 8192) * 256 + threadIdx.x;  // 0..98303
    const int linear = i * 4;
    const int j = linear >> 10;
    const int k0 = linear & 1023;
    const float* W = (j < 128) ? Wq : (j < 256) ? Wk : Wv;
    const int h = j & 127;
    ushort4v p;
    p[0] = f2bf(W[(k0 + 0) * 128 + h]);
    p[1] = f2bf(W[(k0 + 1) * 128 + h]);
    p[2] = f2bf(W[(k0 + 2) * 128 + h]);
    p[3] = f2bf(W[(k0 + 3) * 128 + h]);
    *(ushort4v*)(WbT + linear) = p;
  }
}

// ---------------------------------------------------------------------------
// Kernel 2: QKV projection — 128M x 96N x 64K double-buffered LDS GEMM,
// 1 barrier/iter. Grid = 64 rb x 4 cb = 256 blocks (2/CU, 56 KB LDS).
// Waves 2x2: wave owns 64M x 48N (4 mt x 3 nt accs) -> 24 MFMA / 14 ds_read
// per iter. Rows = 8 chunks of 16B, swizzle slot = (chunk ^ row) & 7.
// Q written pre-scaled by CSCALE. V written transposed (VT[b][h][t]).
// ---------------------------------------------------------------------------
__global__ __launch_bounds__(256) void qkv_proj(const unsigned short* __restrict__ xb,
                                                const unsigned short* __restrict__ WbT,
                                                unsigned short* __restrict__ Qb,
                                                unsigned short* __restrict__ Kb,
                                                unsigned short* __restrict__ VT) {
  __shared__ unsigned short As[2][128 * 64];  // 16 KB each
  __shared__ unsigned short Bs[2][96 * 64];   // 12 KB each

  const int tid  = threadIdx.x;
  const int wave = tid >> 6, lane = tid & 63;
  const int quad = lane >> 4, l15 = lane & 15;
  const int rb = blockIdx.x >> 2, cb = blockIdx.x & 3;
  const int gm0 = rb * 128, gn0 = cb * 96;
  const int wm = wave >> 1, wn = wave & 1;

  const int srow = lane >> 3, sslot = lane & 7;   // staging: 8 rows x 8 slots

  // fragment read offsets (shorts)
  int aoff[4][2], boff[3][2];
#pragma unroll
  for (int mt = 0; mt < 4; ++mt) {
    const int r = wm * 64 + mt * 16 + l15;
#pragma unroll
    for (int ks = 0; ks < 2; ++ks)
      aoff[mt][ks] = r * 64 + (((ks * 4 + quad) ^ r) & 7) * 8;
  }
#pragma unroll
  for (int nt = 0; nt < 3; ++nt) {
    const int r = wn * 48 + nt * 16 + l15;
#pragma unroll
    for (int ks = 0; ks < 2; ++ks)
      boff[nt][ks] = r * 64 + (((ks * 4 + quad) ^ r) & 7) * 8;
  }

  f32x4 acc[4][3];
  const f32x4 zero4 = {0.f, 0.f, 0.f, 0.f};
#pragma unroll
  for (int mt = 0; mt < 4; ++mt)
#pragma unroll
    for (int nt = 0; nt < 3; ++nt) acc[mt][nt] = zero4;

#define STAGE_QKV(buf, kb_)                                                        \
  {                                                                                \
    const int ko = (kb_) * 64;                                                     \
    _Pragma("unroll")                                                              \
    for (int q = 0; q < 4; ++q) {                                                  \
      const int row = q * 32 + wave * 8 + srow;                                    \
      gld16(xb + (size_t)(gm0 + row) * C_ + ko + ((sslot ^ row) & 7) * 8,          \
            &As[buf][(q * 32 + wave * 8) * 64]);                                   \
    }                                                                              \
    _Pragma("unroll")                                                              \
    for (int q = 0; q < 3; ++q) {                                                  \
      const int row = wave * 24 + q * 8 + srow;                                    \
      gld16(WbT + (size_t)(gn0 + row) * C_ + ko + ((sslot ^ row) & 7) * 8,         \
            &Bs[buf][(wave * 24 + q * 8) * 64]);                                   \
    }                                                                              \
  }

  STAGE_QKV(0, 0);

  for (int kb = 0; kb < 16; ++kb) {
    __syncthreads();               // buf[kb&1] staged; prior reads of other done
    if (kb + 1 < 16) STAGE_QKV((kb + 1) & 1, kb + 1);
    const unsigned short* Ac = As[kb & 1];
    const unsigned short* Bc = Bs[kb & 1];
#pragma unroll
    for (int ks = 0; ks < 2; ++ks) {
      short8 b0 = *(const short8*)(Bc + boff[0][ks]);
      short8 b1 = *(const short8*)(Bc + boff[1][ks]);
      short8 b2 = *(const short8*)(Bc + boff[2][ks]);
#pragma unroll
      for (int mt = 0; mt < 4; ++mt) {
        short8 a = *(const short8*)(Ac + aoff[mt][ks]);
        acc[mt][0] = __builtin_amdgcn_mfma_f32_16x16x32_bf16(a, b0, acc[mt][0], 0, 0, 0);
        acc[mt][1] = __builtin_amdgcn_mfma_f32_16x16x32_bf16(a, b1, acc[mt][1], 0, 0, 0);
        acc[mt][2] = __builtin_amdgcn_mfma_f32_16x16x32_bf16(a, b2, acc[mt][2], 0, 0, 0);
      }
    }
  }
#undef STAGE_QKV

  // epilogue: D[row=quad*4+r][col=l15] per 16x16 tile
#pragma unroll
  for (int mt = 0; mt < 4; ++mt) {
    const int row0 = gm0 + wm * 64 + mt * 16 + quad * 4;
#pragma unroll
    for (int nt = 0; nt < 3; ++nt) {
      const int colbase = gn0 + wn * 48 + nt * 16;
      const int col = colbase + l15;
      if (colbase < 128) {          // Q (pre-scaled)
#pragma unroll
        for (int r = 0; r < 4; ++r)
          Qb[(size_t)(row0 + r) * H_ + col] = f2bf(acc[mt][nt][r] * CSCALE);
      } else if (colbase < 256) {   // K
#pragma unroll
        for (int r = 0; r < 4; ++r)
          Kb[(size_t)(row0 + r) * H_ + (col - 128)] = f2bf(acc[mt][nt][r]);
      } else {                      // V, transposed
        const int h = col - 256;
        const int bidx = row0 >> 11;
        const int t0 = row0 & 2047;
        ushort4v pk;
        pk[0] = f2bf(acc[mt][nt][0]); pk[1] = f2bf(acc[mt][nt][1]);
        pk[2] = f2bf(acc[mt][nt][2]); pk[3] = f2bf(acc[mt][nt][3]);
        *(ushort4v*)(VT + (size_t)(bidx * H_ + h) * T_ + t0) = pk;
      }
    }
  }
}

// ---------------------------------------------------------------------------
// Kernel 3: flash attention stage 1. S^T formulation, K AND V double-buffered
// in LDS via swizzled gld16; one barrier per KV tile of 64. Chunk = 8 tiles
// (512 kv). Grid 512: b=bid&3, j=(bid>>2)&31, ch=bid>>7; valid iff ch*8<=j.
// j<8 writes final out; else bf16 partial + (m,l) to ws.  LDS 75 KB (2/CU).
// ---------------------------------------------------------------------------
__global__ __launch_bounds__(256, 2) void attn1(const unsigned short* __restrict__ Qb,
                                                const unsigned short* __restrict__ Kb,
                                                const unsigned short* __restrict__ VT,
                                                unsigned short* __restrict__ Opart,
                                                float* __restrict__ mpart,
                                                float* __restrict__ lpart,
                                                float* __restrict__ out) {
  __shared__ unsigned short Ks[2][64 * 128];   // 16 KB each; 16-slot rows
  __shared__ unsigned short Vs[2][128 * 64];   // 16 KB each; 8-slot rows
  __shared__ unsigned short Pls[4][16 * 72];   // 9 KB, per-wave P, pad 72
  __shared__ float Als[4][16];

  const int bid = blockIdx.x;
  const int b  = bid & 3;
  const int j  = (bid >> 2) & 31;
  const int ch = bid >> 7;
  if (ch * 8 > j) return;
  const int ntiles = min(8, j + 1 - ch * 8);

  const int tid  = threadIdx.x;
  const int wave = tid >> 6, lane = tid & 63;
  const int quad = lane >> 4, l15 = lane & 15;

  const unsigned short* qrow = Qb + (size_t)(b * T_ + j * 64 + wave * 16 + l15) * H_;
  short8 aq[4];
#pragma unroll
  for (int ks = 0; ks < 4; ++ks)
    aq[ks] = *(const short8*)(qrow + ks * 32 + quad * 8);

  const unsigned short* Kb_b = Kb + (size_t)(b * T_) * H_;
  const unsigned short* VT_b = VT + (size_t)(b * H_) * T_;

  const int k_row4 = lane >> 4, k_slot = lane & 15;
  const int v_row8 = lane >> 3, v_slot = lane & 7;

#define STAGE_KV(buf, kv0_)                                                        \
  {                                                                                \
    _Pragma("unroll")                                                              \
    for (int i = 0; i < 4; ++i) {                                                  \
      const int r = wave * 16 + i * 4 + k_row4;                                    \
      const int c2 = (k_slot & 8) | ((k_slot ^ r) & 7);                            \
      gld16(Kb_b + (size_t)((kv0_) + r) * H_ + c2 * 8,                             \
            &Ks[buf][(wave * 16 + i * 4) * 128]);                                  \
    }                                                                              \
    _Pragma("unroll")                                                              \
    for (int i = 0; i < 4; ++i) {                                                  \
      const int h = wave * 32 + i * 8 + v_row8;                                    \
      gld16(VT_b + (size_t)h * T_ + (kv0_) + ((v_slot ^ h) & 7) * 8,               \
            &Vs[buf][(wave * 32 + i * 8) * 64]);                                   \
    }                                                                              \
  }

  STAGE_KV(0, ch * 512);

  const f32x4 zero4 = {0.f, 0.f, 0.f, 0.f};
  f32x4 O[8];
#pragma unroll
  for (int nth = 0; nth < 8; ++nth) O[nth] = zero4;
  float m_ = NEG_BIG, l_ = 0.f;

  for (int t = 0; t < ntiles; ++t) {
    __syncthreads();
    const int kv0 = ch * 512 + t * 64;
    if (t + 1 < ntiles) STAGE_KV((t + 1) & 1, kv0 + 64);

    // ---- S^T = K . Q^T
    const unsigned short* kb = Ks[t & 1];
    f32x4 ST[4];
    ST[0] = zero4; ST[1] = zero4; ST[2] = zero4; ST[3] = zero4;
#pragma unroll
    for (int ntl = 0; ntl < 4; ++ntl) {
      const int kvr = ntl * 16 + l15;
#pragma unroll
      for (int ks = 0; ks < 4; ++ks) {
        const int c = ks * 4 + quad;
        const int slot = (c & 8) | ((c ^ kvr) & 7);
        short8 kf = *(const short8*)(kb + kvr * 128 + slot * 8);
        ST[ntl] = __builtin_amdgcn_mfma_f32_16x16x32_bf16(kf, aq[ks], ST[ntl], 0, 0, 0);
      }
    }

    // ---- causal mask (diagonal tile only)
    if (ch * 8 + t == j) {
      const int ql = j * 64 + wave * 16 + l15;
#pragma unroll
      for (int ntl = 0; ntl < 4; ++ntl)
#pragma unroll
        for (int r = 0; r < 4; ++r) {
          const int kl = kv0 + ntl * 16 + quad * 4 + r;
          if (kl > ql) ST[ntl][r] = NEG_BIG;
        }
    }

    // ---- softmax (per lane q=l15)
    float vmax = ST[0][0];
#pragma unroll
    for (int ntl = 0; ntl < 4; ++ntl)
#pragma unroll
      for (int r = 0; r < 4; ++r) vmax = fmaxf(vmax, ST[ntl][r]);
    vmax = fmaxf(vmax, __shfl_xor(vmax, 16));
    vmax = fmaxf(vmax, __shfl_xor(vmax, 32));
    const float mn = fmaxf(m_, vmax);
    const float alpha = __builtin_amdgcn_exp2f(m_ - mn);
    m_ = mn;
    float s = 0.f;
#pragma unroll
    for (int ntl = 0; ntl < 4; ++ntl)
#pragma unroll
      for (int r = 0; r < 4; ++r) {
        const float p = __builtin_amdgcn_exp2f(ST[ntl][r] - mn);
        ST[ntl][r] = p;
        s += p;
      }
    s += __shfl_xor(s, 16);
    s += __shfl_xor(s, 32);
    l_ = l_ * alpha + s;

    // ---- P -> LDS ([q][kv] layout)
#pragma unroll
    for (int ntl = 0; ntl < 4; ++ntl) {
      ushort4v pk;
      pk[0] = f2bf(ST[ntl][0]); pk[1] = f2bf(ST[ntl][1]);
      pk[2] = f2bf(ST[ntl][2]); pk[3] = f2bf(ST[ntl][3]);
      *(ushort4v*)(&Pls[wave][l15 * 72 + ntl * 16 + quad * 4]) = pk;
    }

    // ---- O rescale by alpha
    if (lane < 16) Als[wave][lane] = alpha;
    if (!__all(alpha == 1.f)) {
      f32x4 al4 = *(const f32x4*)&Als[wave][quad * 4];
#pragma unroll
      for (int nth = 0; nth < 8; ++nth)
#pragma unroll
        for (int r = 0; r < 4; ++r) O[nth][r] *= al4[r];
    }

    // ---- O += P . V
    const unsigned short* vb = Vs[t & 1];
    short8 ap0 = *(const short8*)(&Pls[wave][l15 * 72 + quad * 8]);
    short8 ap1 = *(const short8*)(&Pls[wave][l15 * 72 + 32 + quad * 8]);
#pragma unroll
    for (int nth = 0; nth < 8; ++nth) {
      const int h = nth * 16 + l15;
      short8 v0 = *(const short8*)(vb + h * 64 + ((quad ^ h) & 7) * 8);
      short8 v1 = *(const short8*)(vb + h * 64 + (((4 + quad) ^ h) & 7) * 8);
      O[nth] = __builtin_amdgcn_mfma_f32_16x16x32_bf16(ap0, v0, O[nth], 0, 0, 0);
      O[nth] = __builtin_amdgcn_mfma_f32_16x16x32_bf16(ap1, v1, O[nth], 0, 0, 0);
    }
  }
#undef STAGE_KV

  // ---- epilogue
  if ((j >> 3) == 0) {  // single chunk: final output
    if (lane < 16) Als[wave][lane] = 1.0f / l_;
    f32x4 li4 = *(const f32x4*)&Als[wave][quad * 4];
    float* op = out + (size_t)(b * T_ + j * 64 + wave * 16) * H_;
#pragma unroll
    for (int nth = 0; nth < 8; ++nth)
#pragma unroll
      for (int r = 0; r < 4; ++r)
        op[(quad * 4 + r) * H_ + nth * 16 + l15] = O[nth][r] * li4[r];
  } else {              // partial: un-normalized O (bf16) + m, l
    const int pid = (b * 32 + j) * 4 + ch;
    unsigned short* po = Opart + (size_t)(pid * 64 + wave * 16) * H_;
#pragma unroll
    for (int nth = 0; nth < 8; ++nth)
#pragma unroll
      for (int r = 0; r < 4; ++r)
        po[(quad * 4 + r) * H_ + nth * 16 + l15] = f2bf(O[nth][r]);
    if (lane < 16) {
      mpart[pid * 64 + wave * 16 + lane] = m_;
      lpart[pid * 64 + wave * 16 + lane] = l_;
    }
  }
}

// ---------------------------------------------------------------------------
// Kernel 4: stage-2 combine for j >= 8. Grid = 4 b x 24 j = 96 blocks.
// ---------------------------------------------------------------------------
__global__ __launch_bounds__(256) void attn2(const unsigned short* __restrict__ Opart,
                                             const float* __restrict__ mpart,
                                             const float* __restrict__ lpart,
                                             float* __restrict__ out) {
  const int b = blockIdx.x & 3;
  const int j = 8 + (blockIdx.x >> 2);
  const int nch = (j >> 3) + 1;       // 2..4
  const int tid = threadIdx.x;
  const int qh = tid >> 4;            // 0..15
  const int h0 = (tid & 15) * 8;
  const int pbase = (b * 32 + j) * 4;

#pragma unroll
  for (int i = 0; i < 4; ++i) {
    const int q = qh + i * 16;        // 0..63
    float m_fin = NEG_BIG;
    for (int ch = 0; ch < nch; ++ch)
      m_fin = fmaxf(m_fin, mpart[(pbase + ch) * 64 + q]);
    float lf = 0.f;
    float o[8];
#pragma unroll
    for (int c = 0; c < 8; ++c) o[c] = 0.f;
    for (int ch = 0; ch < nch; ++ch) {
      const int pid = pbase + ch;
      const float sc = __builtin_amdgcn_exp2f(mpart[pid * 64 + q] - m_fin);
      lf += sc * lpart[pid * 64 + q];
      ushort8v pv = *(const ushort8v*)(Opart + (size_t)(pid * 64 + q) * H_ + h0);
#pragma unroll
      for (int c = 0; c < 8; ++c) o[c] += sc * bf2f(pv[c]);
    }
    const float inv = 1.0f / lf;
    float* op = out + (size_t)(b * T_ + j * 64 + q) * H_ + h0;
    f32x4 v0 = {o[0] * inv, o[1] * inv, o[2] * inv, o[3] * inv};
    f32x4 v1 = {o[4] * inv, o[5] * inv, o[6] * inv, o[7] * inv};
    *(f32x4*)(op) = v0;
    *(f32x4*)(op + 4) = v1;
  }
}

// ---------------------------------------------------------------------------
extern "C" void kernel_launch(void* const* d_in, const int* in_sizes, int n_in,
                              void* d_out, int out_size, void* d_ws, size_t ws_size,
                              hipStream_t stream) {
  const float* x  = (const float*)d_in[0];
  const float* Wq = (const float*)d_in[1];
  const float* Wk = (const float*)d_in[2];
  const float* Wv = (const float*)d_in[3];
  float* out = (float*)d_out;

  char* ws = (char*)d_ws;
  unsigned short* xb  = (unsigned short*)(ws);              // [0, 16 MB)
  unsigned short* WbT = (unsigned short*)(ws + 16777216);   // 768 KB
  unsigned short* Qb  = (unsigned short*)(ws + 17563648);   // 2 MB
  unsigned short* Kb  = (unsigned short*)(ws + 19660800);   // 2 MB
  unsigned short* VT  = (unsigned short*)(ws + 21757952);   // 2 MB -> end 23855104
  // attn partials OVERLAY xb (dead after qkv_proj; stream-ordered)
  unsigned short* Opart = (unsigned short*)(ws);            // 512*64*128*2 = 8 MB
  float* mpart = (float*)(ws + 8388608);                    // 128 KB
  float* lpart = (float*)(ws + 8519680);                    // 128 KB (< 16 MB)

  prep<<<dim3(8576), dim3(256), 0, stream>>>(x, Wq, Wk, Wv, xb, WbT);
  qkv_proj<<<dim3(256), dim3(256), 0, stream>>>(xb, WbT, Qb, Kb, VT);
  attn1<<<dim3(512), dim3(256), 0, stream>>>(Qb, Kb, VT, Opart, mpart, lpart, out);
  attn2<<<dim3(96), dim3(256), 0, stream>>>(Opart, mpart, lpart, out);
}

// Round 10
// 136.508 us; speedup vs baseline: 1.7125x; 1.0050x over previous
//
#include <hip/hip_runtime.h>
#include <stdint.h>

#define B_ 4
#define T_ 2048
#define C_ 1024
#define H_ 128
#define NEG_BIG -3.0e38f

typedef __attribute__((ext_vector_type(8))) short short8;
typedef __attribute__((ext_vector_type(4))) float f32x4;
typedef __attribute__((ext_vector_type(4))) unsigned short ushort4v;
typedef __attribute__((ext_vector_type(8))) unsigned short ushort8v;

// cheap bf16 cast: round-half-up, <=0.5 ULP (validated R6-R9: absmax unchanged)
__device__ __forceinline__ unsigned short f2bf(float f) {
  union { float f; unsigned u; } cv; cv.f = f;
  return (unsigned short)((cv.u + 0x8000u) >> 16);
}

__device__ __forceinline__ float bf2f(unsigned short s) {
  union { unsigned u; float f; } cv; cv.u = ((unsigned)s) << 16;
  return cv.f;
}

// async global->LDS, 16 bytes per lane. LDS dest = wave-uniform base + lane*16.
__device__ __forceinline__ void gld16(const void* g, void* l) {
  __builtin_amdgcn_global_load_lds(
      (const __attribute__((address_space(1))) unsigned int*)g,
      (__attribute__((address_space(3))) unsigned int*)l, 16, 0, 0);
}

// scale = C^-0.5 = 1/32; folded with log2(e) for exp2-domain softmax
#define CSCALE 0.045084220027780106f

// ---------------------------------------------------------------------------
// Kernel 1: prep_w — cast Wq|Wk|Wv (fp32 [1024][128]) to WbT bf16 [384][1024]
// (transposed so B-fragments are contiguous). Tiny: ~2.3 MB traffic.
// ---------------------------------------------------------------------------
__global__ __launch_bounds__(256) void prep_w(const float* __restrict__ Wq,
                                              const float* __restrict__ Wk,
                                              const float* __restrict__ Wv,
                                              unsigned short* __restrict__ WbT) {
  const int i = blockIdx.x * 256 + threadIdx.x;   // 0..98303
  const int linear = i * 4;
  const int j = linear >> 10;
  const int k0 = linear & 1023;
  const float* W = (j < 128) ? Wq : (j < 256) ? Wk : Wv;
  const int h = j & 127;
  ushort4v p;
  p[0] = f2bf(W[(k0 + 0) * 128 + h]);
  p[1] = f2bf(W[(k0 + 1) * 128 + h]);
  p[2] = f2bf(W[(k0 + 2) * 128 + h]);
  p[3] = f2bf(W[(k0 + 3) * 128 + h]);
  *(ushort4v*)(WbT + linear) = p;
}

// ---------------------------------------------------------------------------
// Kernel 2: fused x-cast + QKV projection.
// 128M x 96N x 64K double-buffered LDS GEMM, 1 barrier/iter.
// Grid = 64 rb x 4 cb = 256 blocks (2/CU, 56 KB LDS). Waves 2x2: wave owns
// 64M x 48N (4 mt x 3 nt accs) -> 24 MFMA + 14 ds_read_b128 per iter.
// A: x fp32 -> regs -> ONE cvt -> swizzled ds_write_b128 bf16 (no prep pass;
//    thread = row tid>>3 + 32q, chunk tid&7: 8 consecutive floats -> short8).
// B: bf16 gld16 from WbT. Rows = 8 chunks of 16B, slot = (chunk ^ row) & 7.
// Q written pre-scaled by CSCALE. V written transposed (VT[b][h][t]).
// ---------------------------------------------------------------------------
__global__ __launch_bounds__(256) void qkv_proj(const float* __restrict__ x,
                                                const unsigned short* __restrict__ WbT,
                                                unsigned short* __restrict__ Qb,
                                                unsigned short* __restrict__ Kb,
                                                unsigned short* __restrict__ VT) {
  __shared__ unsigned short As[2][128 * 64];  // 16 KB each
  __shared__ unsigned short Bs[2][96 * 64];   // 12 KB each

  const int tid  = threadIdx.x;
  const int wave = tid >> 6, lane = tid & 63;
  const int quad = lane >> 4, l15 = lane & 15;
  const int rb = blockIdx.x >> 2, cb = blockIdx.x & 3;
  const int gm0 = rb * 128, gn0 = cb * 96;
  const int wm = wave >> 1, wn = wave & 1;

  const int srow = lane >> 3, sslot = lane & 7;   // B staging: 8 rows x 8 slots
  // A staging: thread -> (row = tid>>3 (+32q), chunk = tid&7)
  const int axr = tid >> 3, axc = tid & 7;
  const float* gAx = x + (size_t)(gm0 + axr) * C_ + axc * 8;

  // fragment read offsets (shorts)
  int aoff[4][2], boff[3][2];
#pragma unroll
  for (int mt = 0; mt < 4; ++mt) {
    const int r = wm * 64 + mt * 16 + l15;
#pragma unroll
    for (int ks = 0; ks < 2; ++ks)
      aoff[mt][ks] = r * 64 + (((ks * 4 + quad) ^ r) & 7) * 8;
  }
#pragma unroll
  for (int nt = 0; nt < 3; ++nt) {
    const int r = wn * 48 + nt * 16 + l15;
#pragma unroll
    for (int ks = 0; ks < 2; ++ks)
      boff[nt][ks] = r * 64 + (((ks * 4 + quad) ^ r) & 7) * 8;
  }

  f32x4 acc[4][3];
  const f32x4 zero4 = {0.f, 0.f, 0.f, 0.f};
#pragma unroll
  for (int mt = 0; mt < 4; ++mt)
#pragma unroll
    for (int nt = 0; nt < 3; ++nt) acc[mt][nt] = zero4;

  // B staging via async gld16
#define STAGE_B(buf, kb_)                                                          \
  {                                                                                \
    const int ko = (kb_) * 64;                                                     \
    _Pragma("unroll")                                                              \
    for (int q = 0; q < 3; ++q) {                                                  \
      const int row = wave * 24 + q * 8 + srow;                                    \
      gld16(WbT + (size_t)(gn0 + row) * C_ + ko + ((sslot ^ row) & 7) * 8,         \
            &Bs[buf][(wave * 24 + q * 8) * 64]);                                   \
    }                                                                              \
  }

  // A: load fp32 tile (q=0..3 -> rows axr+32q), 2 f32x4 per q
#define LOAD_A(ko_)                                                                \
  _Pragma("unroll")                                                                \
  for (int q = 0; q < 4; ++q) {                                                    \
    av0[q] = *(const f32x4*)(gAx + (size_t)(q * 32) * C_ + (ko_));                 \
    av1[q] = *(const f32x4*)(gAx + (size_t)(q * 32) * C_ + (ko_) + 4);             \
  }

  // A: cvt + swizzled ds_write_b128 into buffer buf
#define WRITE_A(buf)                                                               \
  _Pragma("unroll")                                                                \
  for (int q = 0; q < 4; ++q) {                                                    \
    const int row = axr + q * 32;                                                  \
    short8 aw;                                                                     \
    _Pragma("unroll")                                                              \
    for (int e = 0; e < 4; ++e) {                                                  \
      aw[e]     = (short)f2bf(av0[q][e]);                                          \
      aw[4 + e] = (short)f2bf(av1[q][e]);                                          \
    }                                                                              \
    *(short8*)(&As[buf][row * 64 + ((axc ^ row) & 7) * 8]) = aw;                   \
  }

  f32x4 av0[4], av1[4];
  // preload tile 0
  LOAD_A(0);
  STAGE_B(0, 0);
  WRITE_A(0);

  for (int kb = 0; kb < 16; ++kb) {
    __syncthreads();               // buf[kb&1] staged; prior reads of other done
    const int cur = kb & 1, nxt = cur ^ 1;
    if (kb + 1 < 16) {             // issue next-tile loads right after barrier
      LOAD_A((kb + 1) * 64);
      STAGE_B(nxt, kb + 1);
    }
    const unsigned short* Ac = As[cur];
    const unsigned short* Bc = Bs[cur];
#pragma unroll
    for (int ks = 0; ks < 2; ++ks) {
      short8 b0 = *(const short8*)(Bc + boff[0][ks]);
      short8 b1 = *(const short8*)(Bc + boff[1][ks]);
      short8 b2 = *(const short8*)(Bc + boff[2][ks]);
#pragma unroll
      for (int mt = 0; mt < 4; ++mt) {
        short8 a = *(const short8*)(Ac + aoff[mt][ks]);
        acc[mt][0] = __builtin_amdgcn_mfma_f32_16x16x32_bf16(a, b0, acc[mt][0], 0, 0, 0);
        acc[mt][1] = __builtin_amdgcn_mfma_f32_16x16x32_bf16(a, b1, acc[mt][1], 0, 0, 0);
        acc[mt][2] = __builtin_amdgcn_mfma_f32_16x16x32_bf16(a, b2, acc[mt][2], 0, 0, 0);
      }
    }
    if (kb + 1 < 16) WRITE_A(nxt);  // cvt + write next A after MFMAs issued
  }
#undef STAGE_B
#undef LOAD_A
#undef WRITE_A

  // epilogue: D[row=quad*4+r][col=l15] per 16x16 tile
#pragma unroll
  for (int mt = 0; mt < 4; ++mt) {
    const int row0 = gm0 + wm * 64 + mt * 16 + quad * 4;
#pragma unroll
    for (int nt = 0; nt < 3; ++nt) {
      const int colbase = gn0 + wn * 48 + nt * 16;
      const int col = colbase + l15;
      if (colbase < 128) {          // Q (pre-scaled)
#pragma unroll
        for (int r = 0; r < 4; ++r)
          Qb[(size_t)(row0 + r) * H_ + col] = f2bf(acc[mt][nt][r] * CSCALE);
      } else if (colbase < 256) {   // K
#pragma unroll
        for (int r = 0; r < 4; ++r)
          Kb[(size_t)(row0 + r) * H_ + (col - 128)] = f2bf(acc[mt][nt][r]);
      } else {                      // V, transposed
        const int h = col - 256;
        const int bidx = row0 >> 11;
        const int t0 = row0 & 2047;
        ushort4v pk;
        pk[0] = f2bf(acc[mt][nt][0]); pk[1] = f2bf(acc[mt][nt][1]);
        pk[2] = f2bf(acc[mt][nt][2]); pk[3] = f2bf(acc[mt][nt][3]);
        *(ushort4v*)(VT + (size_t)(bidx * H_ + h) * T_ + t0) = pk;
      }
    }
  }
}

// ---------------------------------------------------------------------------
// Kernel 3: flash attention stage 1 (R9-exact). S^T formulation, K AND V
// double-buffered in LDS via swizzled gld16; one barrier per KV tile of 64.
// Chunk = 8 tiles (512 kv). Grid 512: b=bid&3, j=(bid>>2)&31, ch=bid>>7.
// ---------------------------------------------------------------------------
__global__ __launch_bounds__(256, 2) void attn1(const unsigned short* __restrict__ Qb,
                                                const unsigned short* __restrict__ Kb,
                                                const unsigned short* __restrict__ VT,
                                                unsigned short* __restrict__ Opart,
                                                float* __restrict__ mpart,
                                                float* __restrict__ lpart,
                                                float* __restrict__ out) {
  __shared__ unsigned short Ks[2][64 * 128];   // 16 KB each; 16-slot rows
  __shared__ unsigned short Vs[2][128 * 64];   // 16 KB each; 8-slot rows
  __shared__ unsigned short Pls[4][16 * 72];   // 9 KB, per-wave P, pad 72
  __shared__ float Als[4][16];

  const int bid = blockIdx.x;
  const int b  = bid & 3;
  const int j  = (bid >> 2) & 31;
  const int ch = bid >> 7;
  if (ch * 8 > j) return;
  const int ntiles = min(8, j + 1 - ch * 8);

  const int tid  = threadIdx.x;
  const int wave = tid >> 6, lane = tid & 63;
  const int quad = lane >> 4, l15 = lane & 15;

  const unsigned short* qrow = Qb + (size_t)(b * T_ + j * 64 + wave * 16 + l15) * H_;
  short8 aq[4];
#pragma unroll
  for (int ks = 0; ks < 4; ++ks)
    aq[ks] = *(const short8*)(qrow + ks * 32 + quad * 8);

  const unsigned short* Kb_b = Kb + (size_t)(b * T_) * H_;
  const unsigned short* VT_b = VT + (size_t)(b * H_) * T_;

  const int k_row4 = lane >> 4, k_slot = lane & 15;
  const int v_row8 = lane >> 3, v_slot = lane & 7;

#define STAGE_KV(buf, kv0_)                                                        \
  {                                                                                \
    _Pragma("unroll")                                                              \
    for (int i = 0; i < 4; ++i) {                                                  \
      const int r = wave * 16 + i * 4 + k_row4;                                    \
      const int c2 = (k_slot & 8) | ((k_slot ^ r) & 7);                            \
      gld16(Kb_b + (size_t)((kv0_) + r) * H_ + c2 * 8,                             \
            &Ks[buf][(wave * 16 + i * 4) * 128]);                                  \
    }                                                                              \
    _Pragma("unroll")                                                              \
    for (int i = 0; i < 4; ++i) {                                                  \
      const int h = wave * 32 + i * 8 + v_row8;                                    \
      gld16(VT_b + (size_t)h * T_ + (kv0_) + ((v_slot ^ h) & 7) * 8,               \
            &Vs[buf][(wave * 32 + i * 8) * 64]);                                   \
    }                                                                              \
  }

  STAGE_KV(0, ch * 512);

  const f32x4 zero4 = {0.f, 0.f, 0.f, 0.f};
  f32x4 O[8];
#pragma unroll
  for (int nth = 0; nth < 8; ++nth) O[nth] = zero4;
  float m_ = NEG_BIG, l_ = 0.f;

  for (int t = 0; t < ntiles; ++t) {
    __syncthreads();
    const int kv0 = ch * 512 + t * 64;
    if (t + 1 < ntiles) STAGE_KV((t + 1) & 1, kv0 + 64);

    // ---- S^T = K . Q^T
    const unsigned short* kb = Ks[t & 1];
    f32x4 ST[4];
    ST[0] = zero4; ST[1] = zero4; ST[2] = zero4; ST[3] = zero4;
#pragma unroll
    for (int ntl = 0; ntl < 4; ++ntl) {
      const int kvr = ntl * 16 + l15;
#pragma unroll
      for (int ks = 0; ks < 4; ++ks) {
        const int c = ks * 4 + quad;
        const int slot = (c & 8) | ((c ^ kvr) & 7);
        short8 kf = *(const short8*)(kb + kvr * 128 + slot * 8);
        ST[ntl] = __builtin_amdgcn_mfma_f32_16x16x32_bf16(kf, aq[ks], ST[ntl], 0, 0, 0);
      }
    }

    // ---- causal mask (diagonal tile only)
    if (ch * 8 + t == j) {
      const int ql = j * 64 + wave * 16 + l15;
#pragma unroll
      for (int ntl = 0; ntl < 4; ++ntl)
#pragma unroll
        for (int r = 0; r < 4; ++r) {
          const int kl = kv0 + ntl * 16 + quad * 4 + r;
          if (kl > ql) ST[ntl][r] = NEG_BIG;
        }
    }

    // ---- softmax (per lane q=l15)
    float vmax = ST[0][0];
#pragma unroll
    for (int ntl = 0; ntl < 4; ++ntl)
#pragma unroll
      for (int r = 0; r < 4; ++r) vmax = fmaxf(vmax, ST[ntl][r]);
    vmax = fmaxf(vmax, __shfl_xor(vmax, 16));
    vmax = fmaxf(vmax, __shfl_xor(vmax, 32));
    const float mn = fmaxf(m_, vmax);
    const float alpha = __builtin_amdgcn_exp2f(m_ - mn);
    m_ = mn;
    float s = 0.f;
#pragma unroll
    for (int ntl = 0; ntl < 4; ++ntl)
#pragma unroll
      for (int r = 0; r < 4; ++r) {
        const float p = __builtin_amdgcn_exp2f(ST[ntl][r] - mn);
        ST[ntl][r] = p;
        s += p;
      }
    s += __shfl_xor(s, 16);
    s += __shfl_xor(s, 32);
    l_ = l_ * alpha + s;

    // ---- P -> LDS ([q][kv] layout)
#pragma unroll
    for (int ntl = 0; ntl < 4; ++ntl) {
      ushort4v pk;
      pk[0] = f2bf(ST[ntl][0]); pk[1] = f2bf(ST[ntl][1]);
      pk[2] = f2bf(ST[ntl][2]); pk[3] = f2bf(ST[ntl][3]);
      *(ushort4v*)(&Pls[wave][l15 * 72 + ntl * 16 + quad * 4]) = pk;
    }

    // ---- O rescale by alpha
    if (lane < 16) Als[wave][lane] = alpha;
    if (!__all(alpha == 1.f)) {
      f32x4 al4 = *(const f32x4*)&Als[wave][quad * 4];
#pragma unroll
      for (int nth = 0; nth < 8; ++nth)
#pragma unroll
        for (int r = 0; r < 4; ++r) O[nth][r] *= al4[r];
    }

    // ---- O += P . V
    const unsigned short* vb = Vs[t & 1];
    short8 ap0 = *(const short8*)(&Pls[wave][l15 * 72 + quad * 8]);
    short8 ap1 = *(const short8*)(&Pls[wave][l15 * 72 + 32 + quad * 8]);
#pragma unroll
    for (int nth = 0; nth < 8; ++nth) {
      const int h = nth * 16 + l15;
      short8 v0 = *(const short8*)(vb + h * 64 + ((quad ^ h) & 7) * 8);
      short8 v1 = *(const short8*)(vb + h * 64 + (((4 + quad) ^ h) & 7) * 8);
      O[nth] = __builtin_amdgcn_mfma_f32_16x16x32_bf16(ap0, v0, O[nth], 0, 0, 0);
      O[nth] = __builtin_amdgcn_mfma_f32_16x16x32_bf16(ap1, v1, O[nth], 0, 0, 0);
    }
  }
#undef STAGE_KV

  // ---- epilogue
  if ((j >> 3) == 0) {  // single chunk: final output
    if (lane < 16) Als[wave][lane] = 1.0f / l_;
    f32x4 li4 = *(const f32x4*)&Als[wave][quad * 4];
    float* op = out + (size_t)(b * T_ + j * 64 + wave * 16) * H_;
#pragma unroll
    for (int nth = 0; nth < 8; ++nth)
#pragma unroll
      for (int r = 0; r < 4; ++r)
        op[(quad * 4 + r) * H_ + nth * 16 + l15] = O[nth][r] * li4[r];
  } else {              // partial: un-normalized O (bf16) + m, l
    const int pid = (b * 32 + j) * 4 + ch;
    unsigned short* po = Opart + (size_t)(pid * 64 + wave * 16) * H_;
#pragma unroll
    for (int nth = 0; nth < 8; ++nth)
#pragma unroll
      for (int r = 0; r < 4; ++r)
        po[(quad * 4 + r) * H_ + nth * 16 + l15] = f2bf(O[nth][r]);
    if (lane < 16) {
      mpart[pid * 64 + wave * 16 + lane] = m_;
      lpart[pid * 64 + wave * 16 + lane] = l_;
    }
  }
}

// ---------------------------------------------------------------------------
// Kernel 4: stage-2 combine for j >= 8. Grid = 4 b x 24 j = 96 blocks.
// ---------------------------------------------------------------------------
__global__ __launch_bounds__(256) void attn2(const unsigned short* __restrict__ Opart,
                                             const float* __restrict__ mpart,
                                             const float* __restrict__ lpart,
                                             float* __restrict__ out) {
  const int b = blockIdx.x & 3;
  const int j = 8 + (blockIdx.x >> 2);
  const int nch = (j >> 3) + 1;       // 2..4
  const int tid = threadIdx.x;
  const int qh = tid >> 4;            // 0..15
  const int h0 = (tid & 15) * 8;
  const int pbase = (b * 32 + j) * 4;

#pragma unroll
  for (int i = 0; i < 4; ++i) {
    const int q = qh + i * 16;        // 0..63
    float m_fin = NEG_BIG;
    for (int ch = 0; ch < nch; ++ch)
      m_fin = fmaxf(m_fin, mpart[(pbase + ch) * 64 + q]);
    float lf = 0.f;
    float o[8];
#pragma unroll
    for (int c = 0; c < 8; ++c) o[c] = 0.f;
    for (int ch = 0; ch < nch; ++ch) {
      const int pid = pbase + ch;
      const float sc = __builtin_amdgcn_exp2f(mpart[pid * 64 + q] - m_fin);
      lf += sc * lpart[pid * 64 + q];
      ushort8v pv = *(const ushort8v*)(Opart + (size_t)(pid * 64 + q) * H_ + h0);
#pragma unroll
      for (int c = 0; c < 8; ++c) o[c] += sc * bf2f(pv[c]);
    }
    const float inv = 1.0f / lf;
    float* op = out + (size_t)(b * T_ + j * 64 + q) * H_ + h0;
    f32x4 v0 = {o[0] * inv, o[1] * inv, o[2] * inv, o[3] * inv};
    f32x4 v1 = {o[4] * inv, o[5] * inv, o[6] * inv, o[7] * inv};
    *(f32x4*)(op) = v0;
    *(f32x4*)(op + 4) = v1;
  }
}

// ---------------------------------------------------------------------------
extern "C" void kernel_launch(void* const* d_in, const int* in_sizes, int n_in,
                              void* d_out, int out_size, void* d_ws, size_t ws_size,
                              hipStream_t stream) {
  const float* x  = (const float*)d_in[0];
  const float* Wq = (const float*)d_in[1];
  const float* Wk = (const float*)d_in[2];
  const float* Wv = (const float*)d_in[3];
  float* out = (float*)d_out;

  char* ws = (char*)d_ws;
  unsigned short* WbT = (unsigned short*)(ws);              // [0, 768 KB)
  unsigned short* Qb  = (unsigned short*)(ws + 1048576);    // [1 MB, 3 MB)
  unsigned short* Kb  = (unsigned short*)(ws + 3145728);    // [3 MB, 5 MB)
  unsigned short* VT  = (unsigned short*)(ws + 5242880);    // [5 MB, 7 MB)
  unsigned short* Opart = (unsigned short*)(ws + 8388608);  // [8 MB, 16 MB)
  float* mpart = (float*)(ws + 16777216);                   // 128 KB
  float* lpart = (float*)(ws + 16908288);                   // 128 KB

  prep_w<<<dim3(384), dim3(256), 0, stream>>>(Wq, Wk, Wv, WbT);
  qkv_proj<<<dim3(256), dim3(256), 0, stream>>>(x, WbT, Qb, Kb, VT);
  attn1<<<dim3(512), dim3(256), 0, stream>>>(Qb, Kb, VT, Opart, mpart, lpart, out);
  attn2<<<dim3(96), dim3(256), 0, stream>>>(Opart, mpart, lpart, out);
}